// Round 1
// baseline (750.432 us; speedup 1.0000x reference)
//
#include <hip/hip_runtime.h>

// Problem constants (reference: B=1, T=2048, H=32, D=64, SCALE=1/64, DEG=2)
#define B_DIM 1
#define T_DIM 2048
#define H_DIM 32
#define D_DIM 64
#define SCALE_F 0.015625f
#define QTILE 64
#define STILE 64

// ---------------------------------------------------------------------------
// Kernel 1: per-(b,h) inclusive cumsum of g over T -> gc stored [B*H][T]
// ---------------------------------------------------------------------------
__global__ __launch_bounds__(256)
void cumsum_g_kernel(const float* __restrict__ g, float* __restrict__ gc,
                     int B, int T, int H) {
    const int bh = blockIdx.x;          // b*H + h
    const int b = bh / H;
    const int h = bh % H;
    const int tid = threadIdx.x;
    const int PER = T / 256;            // 8 for T=2048

    __shared__ float sums[256];

    float loc[8];
    float run = 0.f;
    const int t0 = tid * PER;
    for (int i = 0; i < PER; ++i) {
        run += g[((size_t)b * T + t0 + i) * H + h];
        loc[i] = run;
    }
    sums[tid] = run;
    __syncthreads();

    // Hillis-Steele inclusive scan over 256 per-thread totals
    for (int off = 1; off < 256; off <<= 1) {
        float vv = (tid >= off) ? sums[tid - off] : 0.f;
        __syncthreads();
        sums[tid] += vv;
        __syncthreads();
    }
    float excl = (tid == 0) ? 0.f : sums[tid - 1];

    for (int i = 0; i < PER; ++i) {
        gc[(size_t)bh * T + t0 + i] = excl + loc[i];
    }
}

// ---------------------------------------------------------------------------
// Kernel 2: power retention deg=2, quadratic (attention) form, fp32.
// Block: one head h, 64 q-rows. 256 threads = 64 rows x 4 col-groups.
// Thread (row, c) owns output dims [c*16, c*16+16).
// For each s-tile (64 K/V rows staged in LDS):
//   qk = dot(q_row, k_s) * SCALE   (4-lane shuffle reduce)
//   w  = qk^2 * exp(gc_t - gc_s)   (factored via tile base to avoid overflow)
//   denom += w; acc[j] += w * v_s[j]
// ---------------------------------------------------------------------------
__global__ __launch_bounds__(256)
void retention_fwd_kernel(const float* __restrict__ q,
                          const float* __restrict__ k,
                          const float* __restrict__ v,
                          const float* __restrict__ gc,
                          float* __restrict__ out,
                          int B, int T, int H) {
    const int tile = blockIdx.x;      // q-tile
    const int h    = blockIdx.y;
    const int b    = blockIdx.z;
    const int t0   = tile * QTILE;

    const int tid = threadIdx.x;
    const int row = tid >> 2;         // 0..63
    const int c   = tid & 3;          // 0..3
    const int t   = t0 + row;

    __shared__ float kt[STILE][D_DIM];   // 16 KB
    __shared__ float vt[STILE][D_DIM];   // 16 KB
    __shared__ float es[STILE];

    const float* gch = gc + (size_t)(b * H + h) * T;
    const float gct = gch[t];

    // Q fragment: 16 floats of row t, dims [c*16, c*16+16)
    float qf[16];
    const float* qrow = q + (((size_t)b * T + t) * H + h) * D_DIM + c * 16;
#pragma unroll
    for (int j = 0; j < 4; ++j) {
        float4 f = *reinterpret_cast<const float4*>(qrow + j * 4);
        qf[j * 4 + 0] = f.x; qf[j * 4 + 1] = f.y;
        qf[j * 4 + 2] = f.z; qf[j * 4 + 3] = f.w;
    }

    float acc[16];
#pragma unroll
    for (int j = 0; j < 16; ++j) acc[j] = 0.f;
    float denom = 0.f;

    const int ntiles = tile + 1;
    for (int st = 0; st < ntiles; ++st) {
        const int s0 = st * STILE;

        __syncthreads();  // protect LDS from previous iteration's readers
        // Stage K/V tile: 64 rows x 64 cols fp32, 256 threads x 4 float4 each
        for (int i = tid; i < STILE * 16; i += 256) {
            const int srow = i >> 4;
            const int ccol = (i & 15) * 4;
            const size_t gidx = (((size_t)b * T + s0 + srow) * H + h) * D_DIM + ccol;
            *reinterpret_cast<float4*>(&kt[srow][ccol]) =
                *reinterpret_cast<const float4*>(k + gidx);
            *reinterpret_cast<float4*>(&vt[srow][ccol]) =
                *reinterpret_cast<const float4*>(v + gidx);
        }
        if (tid < STILE) {
            // e_s = exp(gc_base - gc_s) in [1, e^6.4] — no overflow
            es[tid] = __expf(gch[s0] - gch[s0 + tid]);
        }
        __syncthreads();

        // e_t = exp(gc_t - gc_base) <= 1 (underflows to 0 harmlessly)
        const float et = __expf(gct - gch[s0]);

        // diagonal tile: only s_local <= row valid; other tiles: all valid
        const int smax = (st == tile - 0 && s0 == t0) ? (row + 1) : STILE;

#pragma unroll 4
        for (int sl = 0; sl < STILE; ++sl) {
            float part = 0.f;
            const float* kr = &kt[sl][c * 16];
#pragma unroll
            for (int j = 0; j < 16; ++j) part = fmaf(qf[j], kr[j], part);
            // reduce across the 4 col-groups of this row (lanes c^1, c^2)
            part += __shfl_xor(part, 1);
            part += __shfl_xor(part, 2);
            const float qk = part * SCALE_F;
            float w = qk * qk * (et * es[sl]);
            w = (sl < smax) ? w : 0.f;
            denom += w;
            const float* vr = &vt[sl][c * 16];
#pragma unroll
            for (int j = 0; j < 16; ++j) acc[j] = fmaf(w, vr[j], acc[j]);
        }
    }

    const float inv = 1.f / fmaxf(denom, 1.0f);
    float* orow = out + (((size_t)b * T + t) * H + h) * D_DIM + c * 16;
#pragma unroll
    for (int j = 0; j < 4; ++j) {
        float4 f;
        f.x = acc[j * 4 + 0] * inv; f.y = acc[j * 4 + 1] * inv;
        f.z = acc[j * 4 + 2] * inv; f.w = acc[j * 4 + 3] * inv;
        *reinterpret_cast<float4*>(orow + j * 4) = f;
    }
}

// ---------------------------------------------------------------------------
extern "C" void kernel_launch(void* const* d_in, const int* in_sizes, int n_in,
                              void* d_out, int out_size, void* d_ws, size_t ws_size,
                              hipStream_t stream) {
    const float* q = (const float*)d_in[0];
    const float* k = (const float*)d_in[1];
    const float* v = (const float*)d_in[2];
    const float* g = (const float*)d_in[3];
    float* out = (float*)d_out;

    const int B = B_DIM, T = T_DIM, H = H_DIM;
    float* gc = (float*)d_ws;   // B*H*T floats = 256 KB

    cumsum_g_kernel<<<B * H, 256, 0, stream>>>(g, gc, B, T, H);

    dim3 grid(T / QTILE, H, B);
    retention_fwd_kernel<<<grid, 256, 0, stream>>>(q, k, v, gc, out, B, T, H);
}

// Round 2
// 528.828 us; speedup vs baseline: 1.4190x; 1.4190x over previous
//
#include <hip/hip_runtime.h>

// Problem constants (reference: B=1, T=2048, H=32, D=64, SCALE=1/64, DEG=2)
#define T_DIM 2048
#define H_DIM 32
#define D_DIM 64
#define SCALE_F 0.015625f
#define QTILE 64
#define STILE 64
#define NT (T_DIM / QTILE)      // 32 q-tiles
#define NPAIR (NT / 2)          // 16 folded pairs

// ---------------------------------------------------------------------------
// Kernel 1: per-head inclusive cumsum of g over T -> gc stored [H][T]  (B=1)
// ---------------------------------------------------------------------------
__global__ __launch_bounds__(256)
void cumsum_g_kernel(const float* __restrict__ g, float* __restrict__ gc) {
    const int h = blockIdx.x;
    const int tid = threadIdx.x;
    const int PER = T_DIM / 256;        // 8

    __shared__ float sums[256];

    float loc[8];
    float run = 0.f;
    const int t0 = tid * PER;
    for (int i = 0; i < PER; ++i) {
        run += g[(size_t)(t0 + i) * H_DIM + h];
        loc[i] = run;
    }
    sums[tid] = run;
    __syncthreads();

    for (int off = 1; off < 256; off <<= 1) {
        float vv = (tid >= off) ? sums[tid - off] : 0.f;
        __syncthreads();
        sums[tid] += vv;
        __syncthreads();
    }
    float excl = (tid == 0) ? 0.f : sums[tid - 1];

    for (int i = 0; i < PER; ++i)
        gc[(size_t)h * T_DIM + t0 + i] = excl + loc[i];
}

// ---------------------------------------------------------------------------
// Inner s-tile loop, mode-templated to avoid per-sl masks/branches.
// MODE 0: A full + B full | 1: A diag + B full | 2: B full only | 3: B diag
// kt rows are pre-scaled by sqrt(es[sl]) = exp((gc_base - gc_s)/2), so
//   w = (dot * SCALE)^2 * exp(gc_t - gc_s) = dot'^2 * et'   with
//   et' = exp(gc_t - gc_base) * SCALE^2.
// ---------------------------------------------------------------------------
template<int MODE>
__device__ __forceinline__ void tile_inner(
    const float (*kt)[D_DIM], const float (*vt)[D_DIM],
    int row, int c,
    const float (&qfA)[16], const float (&qfB)[16],
    float etA, float etB,
    float (&accA)[16], float (&accB)[16],
    float& denA, float& denB)
{
    constexpr bool DOA = (MODE <= 1);
#pragma unroll 4
    for (int sl = 0; sl < STILE; ++sl) {
        const float* kr = &kt[sl][c * 16];
        const float* vr = &vt[sl][c * 16];
        float kf[16], vf[16];
#pragma unroll
        for (int j = 0; j < 4; ++j) {
            float4 a = *reinterpret_cast<const float4*>(kr + 4 * j);
            kf[4*j+0] = a.x; kf[4*j+1] = a.y; kf[4*j+2] = a.z; kf[4*j+3] = a.w;
            float4 b = *reinterpret_cast<const float4*>(vr + 4 * j);
            vf[4*j+0] = b.x; vf[4*j+1] = b.y; vf[4*j+2] = b.z; vf[4*j+3] = b.w;
        }

        // --- dots (4 partial chains each for ILP) ---
        float bp0 = 0.f, bp1 = 0.f, bp2 = 0.f, bp3 = 0.f;
#pragma unroll
        for (int j = 0; j < 4; ++j) {
            bp0 = fmaf(qfB[4*j+0], kf[4*j+0], bp0);
            bp1 = fmaf(qfB[4*j+1], kf[4*j+1], bp1);
            bp2 = fmaf(qfB[4*j+2], kf[4*j+2], bp2);
            bp3 = fmaf(qfB[4*j+3], kf[4*j+3], bp3);
        }
        float pb = (bp0 + bp1) + (bp2 + bp3);

        float pa = 0.f;
        if (DOA) {
            float ap0 = 0.f, ap1 = 0.f, ap2 = 0.f, ap3 = 0.f;
#pragma unroll
            for (int j = 0; j < 4; ++j) {
                ap0 = fmaf(qfA[4*j+0], kf[4*j+0], ap0);
                ap1 = fmaf(qfA[4*j+1], kf[4*j+1], ap1);
                ap2 = fmaf(qfA[4*j+2], kf[4*j+2], ap2);
                ap3 = fmaf(qfA[4*j+3], kf[4*j+3], ap3);
            }
            pa = (ap0 + ap1) + (ap2 + ap3);
        }

        // --- reduce across the 4 col-groups of this row ---
        pb += __shfl_xor(pb, 1);
        pb += __shfl_xor(pb, 2);
        if (DOA) {
            pa += __shfl_xor(pa, 1);
            pa += __shfl_xor(pa, 2);
        }

        float wB = pb * pb * etB;
        if (MODE == 3) wB = (sl <= row) ? wB : 0.f;
        denB += wB;
#pragma unroll
        for (int j = 0; j < 16; ++j) accB[j] = fmaf(wB, vf[j], accB[j]);

        if (DOA) {
            float wA = pa * pa * etA;
            if (MODE == 1) wA = (sl <= row) ? wA : 0.f;
            denA += wA;
#pragma unroll
            for (int j = 0; j < 16; ++j) accA[j] = fmaf(wA, vf[j], accA[j]);
        }
    }
}

// ---------------------------------------------------------------------------
// Kernel 2: power retention deg=2, fp32, pair-folded for load balance.
// Block handles q-tiles A=pair and B=NT-1-pair (uniform 33 s-tile stages).
// 256 threads = 64 rows x 4 col-groups; thread owns dims [c*16, c*16+16).
// ---------------------------------------------------------------------------
__global__ __launch_bounds__(256)
void retention_fwd_kernel(const float* __restrict__ q,
                          const float* __restrict__ k,
                          const float* __restrict__ v,
                          const float* __restrict__ gc,
                          float* __restrict__ out) {
    const int pair  = blockIdx.x;        // 0..15
    const int h     = blockIdx.y;
    const int A     = pair;
    const int Btile = NT - 1 - pair;     // > A always

    const int tid = threadIdx.x;
    const int row = tid >> 2;            // 0..63
    const int c   = tid & 3;             // 0..3
    const int tA  = A * QTILE + row;
    const int tB  = Btile * QTILE + row;

    __shared__ float kt[STILE][D_DIM];   // 16 KB (rows pre-scaled by sqrt(es))
    __shared__ float vt[STILE][D_DIM];   // 16 KB

    const float* gch = gc + (size_t)h * T_DIM;
    const float gctA = gch[tA];
    const float gctB = gch[tB];

    // Q fragments
    float qfA[16], qfB[16];
    {
        const float* qra = q + ((size_t)tA * H_DIM + h) * D_DIM + c * 16;
        const float* qrb = q + ((size_t)tB * H_DIM + h) * D_DIM + c * 16;
#pragma unroll
        for (int j = 0; j < 4; ++j) {
            float4 fa = *reinterpret_cast<const float4*>(qra + 4 * j);
            qfA[4*j+0] = fa.x; qfA[4*j+1] = fa.y; qfA[4*j+2] = fa.z; qfA[4*j+3] = fa.w;
            float4 fb = *reinterpret_cast<const float4*>(qrb + 4 * j);
            qfB[4*j+0] = fb.x; qfB[4*j+1] = fb.y; qfB[4*j+2] = fb.z; qfB[4*j+3] = fb.w;
        }
    }

    float accA[16], accB[16];
#pragma unroll
    for (int j = 0; j < 16; ++j) { accA[j] = 0.f; accB[j] = 0.f; }
    float denA = 0.f, denB = 0.f;

    for (int st = 0; st <= Btile; ++st) {
        const int s0 = st * STILE;

        __syncthreads();                 // protect LDS from previous readers
        const float gb = gch[s0];

        // Stage K (scaled by sqrt(es)) and V: 256 threads x 4 float4 each
        for (int i = tid; i < STILE * 16; i += 256) {
            const int srow = i >> 4;
            const int ccol = (i & 15) * 4;
            const float se = __expf((gb - gch[s0 + srow]) * 0.5f); // >= 1, <= ~25
            const size_t gidx = ((size_t)(s0 + srow) * H_DIM + h) * D_DIM + ccol;
            float4 kf4 = *reinterpret_cast<const float4*>(k + gidx);
            kf4.x *= se; kf4.y *= se; kf4.z *= se; kf4.w *= se;
            *reinterpret_cast<float4*>(&kt[srow][ccol]) = kf4;
            *reinterpret_cast<float4*>(&vt[srow][ccol]) =
                *reinterpret_cast<const float4*>(v + gidx);
        }
        __syncthreads();

        const float etA = __expf(gctA - gb) * (SCALE_F * SCALE_F);
        const float etB = __expf(gctB - gb) * (SCALE_F * SCALE_F);

        if (st < A)
            tile_inner<0>(kt, vt, row, c, qfA, qfB, etA, etB, accA, accB, denA, denB);
        else if (st == A)
            tile_inner<1>(kt, vt, row, c, qfA, qfB, etA, etB, accA, accB, denA, denB);
        else if (st < Btile)
            tile_inner<2>(kt, vt, row, c, qfA, qfB, etA, etB, accA, accB, denA, denB);
        else
            tile_inner<3>(kt, vt, row, c, qfA, qfB, etA, etB, accA, accB, denA, denB);
    }

    // Epilogue
    {
        const float invA = 1.f / fmaxf(denA, 1.0f);
        const float invB = 1.f / fmaxf(denB, 1.0f);
        float* oa = out + ((size_t)tA * H_DIM + h) * D_DIM + c * 16;
        float* ob = out + ((size_t)tB * H_DIM + h) * D_DIM + c * 16;
#pragma unroll
        for (int j = 0; j < 4; ++j) {
            float4 fa, fb;
            fa.x = accA[4*j+0] * invA; fa.y = accA[4*j+1] * invA;
            fa.z = accA[4*j+2] * invA; fa.w = accA[4*j+3] * invA;
            *reinterpret_cast<float4*>(oa + 4 * j) = fa;
            fb.x = accB[4*j+0] * invB; fb.y = accB[4*j+1] * invB;
            fb.z = accB[4*j+2] * invB; fb.w = accB[4*j+3] * invB;
            *reinterpret_cast<float4*>(ob + 4 * j) = fb;
        }
    }
}

// ---------------------------------------------------------------------------
extern "C" void kernel_launch(void* const* d_in, const int* in_sizes, int n_in,
                              void* d_out, int out_size, void* d_ws, size_t ws_size,
                              hipStream_t stream) {
    const float* q = (const float*)d_in[0];
    const float* k = (const float*)d_in[1];
    const float* v = (const float*)d_in[2];
    const float* g = (const float*)d_in[3];
    float* out = (float*)d_out;

    float* gc = (float*)d_ws;   // H*T floats = 256 KB

    cumsum_g_kernel<<<H_DIM, 256, 0, stream>>>(g, gc);

    dim3 grid(NPAIR, H_DIM);
    retention_fwd_kernel<<<grid, 256, 0, stream>>>(q, k, v, gc, out);
}

// Round 3
// 86.859 us; speedup vs baseline: 8.6397x; 6.0884x over previous
//
#include <hip/hip_runtime.h>

// Problem constants (reference: B=1, T=2048, H=32, D=64, SCALE=1/64, DEG=2)
#define T_DIM 2048
#define H_DIM 32
#define D_DIM 64
#define SCALE_F 0.015625f
#define QTILE 64
#define STILE 64
#define NT (T_DIM / QTILE)      // 32 q-tiles
#define NPAIR (NT / 2)          // 16 folded pairs

typedef unsigned short ushort;
typedef __attribute__((ext_vector_type(8))) short short8;   // 8 bf16 (4 VGPR)
typedef __attribute__((ext_vector_type(16))) float f32x16;  // MFMA 32x32 acc

// ---------------------------------------------------------------------------
// Kernel 1: per-head inclusive cumsum of g over T -> gc stored [H][T]  (B=1)
// ---------------------------------------------------------------------------
__global__ __launch_bounds__(256)
void cumsum_g_kernel(const float* __restrict__ g, float* __restrict__ gc) {
    const int h = blockIdx.x;
    const int tid = threadIdx.x;
    const int PER = T_DIM / 256;        // 8

    __shared__ float sums[256];

    float loc[8];
    float run = 0.f;
    const int t0 = tid * PER;
    for (int i = 0; i < PER; ++i) {
        run += g[(size_t)(t0 + i) * H_DIM + h];
        loc[i] = run;
    }
    sums[tid] = run;
    __syncthreads();

    for (int off = 1; off < 256; off <<= 1) {
        float vv = (tid >= off) ? sums[tid - off] : 0.f;
        __syncthreads();
        sums[tid] += vv;
        __syncthreads();
    }
    float excl = (tid == 0) ? 0.f : sums[tid - 1];

    for (int i = 0; i < PER; ++i)
        gc[(size_t)h * T_DIM + t0 + i] = excl + loc[i];
}

// ---------------------------------------------------------------------------
// f32 -> bf16 RNE
// ---------------------------------------------------------------------------
__device__ __forceinline__ ushort f2bf(float x) {
    unsigned u = __float_as_uint(x);
    unsigned r = (u + 0x7fffu + ((u >> 16) & 1u)) >> 16;
    return (ushort)r;
}

// ---------------------------------------------------------------------------
// Kernel 2 (prep): q̂ = q*SCALE*exp(gc/2), k̂ = k*exp(-gc/2)  -> [H][T][64] bf16
//                  V̂ᵀ = v^T (bf16)                           -> [H][64][T]
// grid (T/64, H), 256 threads.
// ---------------------------------------------------------------------------
__global__ __launch_bounds__(256)
void prep_kernel(const float* __restrict__ q, const float* __restrict__ k,
                 const float* __restrict__ v, const float* __restrict__ gc,
                 ushort* __restrict__ qh, ushort* __restrict__ kh,
                 ushort* __restrict__ vT) {
    __shared__ ushort vt_lds[64][72];    // [d][t_local], padded
    const int tt  = blockIdx.x;          // t-tile
    const int h   = blockIdx.y;
    const int tid = threadIdx.x;
    const int r   = tid >> 2;            // 0..63 (t_local)
    const int seg = (tid & 3) * 16;      // d segment
    const int t   = tt * 64 + r;

    const float gct = gc[(size_t)h * T_DIM + t];
    const float eq = SCALE_F * __expf(0.5f * gct);
    const float ek = __expf(-0.5f * gct);

    const float* qp = q + ((size_t)t * H_DIM + h) * 64 + seg;
    const float* kp = k + ((size_t)t * H_DIM + h) * 64 + seg;
    const float* vp = v + ((size_t)t * H_DIM + h) * 64 + seg;

    union { ushort u[16]; uint4 q4[2]; } oq, ok;
#pragma unroll
    for (int i = 0; i < 16; ++i) {
        oq.u[i] = f2bf(qp[i] * eq);
        ok.u[i] = f2bf(kp[i] * ek);
        vt_lds[seg + i][r] = f2bf(vp[i]);
    }
    ushort* qo = qh + ((size_t)h * T_DIM + t) * 64 + seg;
    ushort* ko = kh + ((size_t)h * T_DIM + t) * 64 + seg;
    reinterpret_cast<uint4*>(qo)[0] = oq.q4[0];
    reinterpret_cast<uint4*>(qo)[1] = oq.q4[1];
    reinterpret_cast<uint4*>(ko)[0] = ok.q4[0];
    reinterpret_cast<uint4*>(ko)[1] = ok.q4[1];

    __syncthreads();
    // write V̂ᵀ rows: d = r, t-seg = (tid&3)*16
    const int d = r;
    const int tseg = (tid & 3) * 16;
    union { ushort u[16]; uint4 q4[2]; } tv;
#pragma unroll
    for (int i = 0; i < 16; ++i) tv.u[i] = vt_lds[d][tseg + i];
    ushort* vo = vT + ((size_t)h * 64 + d) * T_DIM + tt * 64 + tseg;
    reinterpret_cast<uint4*>(vo)[0] = tv.q4[0];
    reinterpret_cast<uint4*>(vo)[1] = tv.q4[1];
}

// ---------------------------------------------------------------------------
// MFMA main kernel helpers
// ---------------------------------------------------------------------------
__device__ __forceinline__ short8 ld8(const ushort* p) {
    return *reinterpret_cast<const short8*>(p);
}

__device__ __forceinline__ unsigned cvt_pk_bf16(float lo, float hi) {
    unsigned r;
    asm("v_cvt_pk_bf16_f32 %0, %1, %2" : "=v"(r) : "v"(lo), "v"(hi));
    return r;
}

// One 64-s-tile step for one wave-quadrant (sr, tc).
// St^T = K̂·Q̂^T (32x32 quadrant), square+mask, pack W via cvt_pk+permlane32,
// PV: O[t][d] += W·V̂ for both 32-d halves, K = this wave's 32 s.
template<bool DIAG>
__device__ __forceinline__ void do_tile(
    int s0, int sr, int hi, int l31, int h,
    const ushort* __restrict__ kh, const ushort* __restrict__ vT,
    const short8 (&qf)[4],
    f32x16& o0, f32x16& o1, float& den)
{
    // V B-frags [kh][dc] — issued first so latency hides under St MFMAs
    const ushort* vb0 = vT + ((size_t)h * 64 + l31) * T_DIM + s0 + 32 * sr + 8 * hi;
    const short8 vf00 = ld8(vb0);
    const short8 vf10 = ld8(vb0 + 16);
    const ushort* vb1 = vb0 + (size_t)32 * T_DIM;
    const short8 vf01 = ld8(vb1);
    const short8 vf11 = ld8(vb1 + 16);

    // K A-frags (4 k-steps of d)
    const ushort* kb = kh + ((size_t)h * T_DIM + s0 + 32 * sr + l31) * 64 + 8 * hi;
    const short8 kf0 = ld8(kb);
    const short8 kf1 = ld8(kb + 16);
    const short8 kf2 = ld8(kb + 32);
    const short8 kf3 = ld8(kb + 48);

    f32x16 c;
#pragma unroll
    for (int i = 0; i < 16; ++i) c[i] = 0.f;
    c = __builtin_amdgcn_mfma_f32_32x32x16_bf16(kf0, qf[0], c, 0, 0, 0);
    c = __builtin_amdgcn_mfma_f32_32x32x16_bf16(kf1, qf[1], c, 0, 0, 0);
    c = __builtin_amdgcn_mfma_f32_32x32x16_bf16(kf2, qf[2], c, 0, 0, 0);
    c = __builtin_amdgcn_mfma_f32_32x32x16_bf16(kf3, qf[3], c, 0, 0, 0);

    // square (+causal mask on diagonal quadrants, only called with sr==tc)
    float w[16];
#pragma unroll
    for (int r = 0; r < 16; ++r) {
        float x = c[r];
        float ww = x * x;
        if (DIAG) {
            const int off = (r & 3) + 8 * (r >> 2) + 4 * hi;  // s_local in [0,32)
            ww = (off <= l31) ? ww : 0.f;
        }
        w[r] = ww;
        den += ww;
    }

    // pack to PV A-frags per k-half and accumulate PV
#pragma unroll
    for (int khh = 0; khh < 2; ++khh) {
        const int b = 8 * khh;
        unsigned p0 = cvt_pk_bf16(w[b + 0], w[b + 1]);
        unsigned p1 = cvt_pk_bf16(w[b + 2], w[b + 3]);
        unsigned p2 = cvt_pk_bf16(w[b + 4], w[b + 5]);
        unsigned p3 = cvt_pk_bf16(w[b + 6], w[b + 7]);
        asm("v_permlane32_swap_b32 %0, %1" : "+v"(p0), "+v"(p2));
        asm("v_permlane32_swap_b32 %0, %1" : "+v"(p1), "+v"(p3));
        union { unsigned u[4]; short8 s; } af;
        af.u[0] = p0; af.u[1] = p1; af.u[2] = p2; af.u[3] = p3;
        if (khh == 0) {
            o0 = __builtin_amdgcn_mfma_f32_32x32x16_bf16(af.s, vf00, o0, 0, 0, 0);
            o1 = __builtin_amdgcn_mfma_f32_32x32x16_bf16(af.s, vf01, o1, 0, 0, 0);
        } else {
            o0 = __builtin_amdgcn_mfma_f32_32x32x16_bf16(af.s, vf10, o0, 0, 0, 0);
            o1 = __builtin_amdgcn_mfma_f32_32x32x16_bf16(af.s, vf11, o1, 0, 0, 0);
        }
    }
}

__device__ __forceinline__ void process_qtile(
    int qt, int h, int sr, int tc, int hi, int l31,
    const ushort* __restrict__ qh, const ushort* __restrict__ kh,
    const ushort* __restrict__ vT, float* __restrict__ out,
    float* lds_o, float* lds_den)
{
    const int t0 = qt * 64;

    // Q B-frags (fixed per q-tile): col t = l31 within tc-half, k-step d
    short8 qf[4];
    const ushort* qb = qh + ((size_t)h * T_DIM + t0 + 32 * tc + l31) * 64 + 8 * hi;
#pragma unroll
    for (int ks = 0; ks < 4; ++ks) qf[ks] = ld8(qb + 16 * ks);

    f32x16 o0, o1;
#pragma unroll
    for (int i = 0; i < 16; ++i) { o0[i] = 0.f; o1[i] = 0.f; }
    float den = 0.f;

    for (int st = 0; st < qt; ++st)
        do_tile<false>(st * 64, sr, hi, l31, h, kh, vT, qf, o0, o1, den);
    // diagonal s-tile: (0,0),(1,1) masked; (0,1) full; (1,0) all-invalid -> skip
    if (sr == tc)
        do_tile<true>(qt * 64, sr, hi, l31, h, kh, vT, qf, o0, o1, den);
    else if (sr == 0)
        do_tile<false>(qt * 64, sr, hi, l31, h, kh, vT, qf, o0, o1, den);

    den += __shfl_xor(den, 32);   // sum the two hi-groups (same t cols)

    // cross-wave reduction: waves sr=1 -> LDS, waves sr=0 finalize
    __syncthreads();
    if (sr == 1) {
#pragma unroll
        for (int r = 0; r < 16; ++r) {
            const int row = (r & 3) + 8 * (r >> 2) + 4 * hi;
            lds_o[((tc * 2 + 0) * 32 + row) * 32 + l31] = o0[r];
            lds_o[((tc * 2 + 1) * 32 + row) * 32 + l31] = o1[r];
        }
        if ((threadIdx.x & 63) < 32) lds_den[tc * 32 + l31] = den;
    }
    __syncthreads();
    if (sr == 0) {
        const float dtot = lds_den[tc * 32 + l31] + den;   // total denom for t=l31
#pragma unroll
        for (int r = 0; r < 16; ++r) {
            const int row = (r & 3) + 8 * (r >> 2) + 4 * hi;
            const float d0 = o0[r] + lds_o[((tc * 2 + 0) * 32 + row) * 32 + l31];
            const float d1 = o1[r] + lds_o[((tc * 2 + 1) * 32 + row) * 32 + l31];
            const float dt = __shfl(dtot, row);            // lane 'row' holds denom
            const float inv = 1.f / fmaxf(dt, 1.f);
            const size_t ob = ((size_t)(t0 + 32 * tc + row) * H_DIM + h) * 64;
            out[ob + l31]      = d0 * inv;
            out[ob + 32 + l31] = d1 * inv;
        }
    }
}

// ---------------------------------------------------------------------------
// Kernel 3: MFMA retention. 512 blocks (pair-folded), 4 waves/block.
// Wave w: sr=w>>1 (s-half), tc=w&1 (t-col half).
// ---------------------------------------------------------------------------
__global__ __launch_bounds__(256, 2)
void retention_mfma_kernel(const ushort* __restrict__ qh,
                           const ushort* __restrict__ kh,
                           const ushort* __restrict__ vT,
                           float* __restrict__ out) {
    __shared__ float lds_o[2 * 2 * 32 * 32];   // [tc][dc][row][col] partials
    __shared__ float lds_den[64];

    // XCD-grouping swizzle: dispatch slot (bid&7) picks head group so blocks
    // sharing a head land on the same XCD's L2.
    const int bid  = blockIdx.x;
    const int slot = bid & 7;
    const int j    = bid >> 3;
    const int pair = j & 15;
    const int h    = slot + ((j >> 4) << 3);
    const int A    = pair;
    const int Bt   = NT - 1 - pair;

    const int lane = threadIdx.x & 63;
    const int wv   = threadIdx.x >> 6;
    const int sr   = wv >> 1;
    const int tc   = wv & 1;
    const int hi   = lane >> 5;
    const int l31  = lane & 31;

    process_qtile(Bt, h, sr, tc, hi, l31, qh, kh, vT, out, lds_o, lds_den);
    process_qtile(A,  h, sr, tc, hi, l31, qh, kh, vT, out, lds_o, lds_den);
}

// ---------------------------------------------------------------------------
// Fallback fp32 path (R2 kernel) — used only if ws_size is too small.
// ---------------------------------------------------------------------------
template<int MODE>
__device__ __forceinline__ void tile_inner_fb(
    const float (*kt)[D_DIM], const float (*vt)[D_DIM],
    int row, int c,
    const float (&qfA)[16], const float (&qfB)[16],
    float etA, float etB,
    float (&accA)[16], float (&accB)[16],
    float& denA, float& denB)
{
    constexpr bool DOA = (MODE <= 1);
#pragma unroll 4
    for (int sl = 0; sl < STILE; ++sl) {
        const float* kr = &kt[sl][c * 16];
        const float* vr = &vt[sl][c * 16];
        float kf[16], vf[16];
#pragma unroll
        for (int j = 0; j < 4; ++j) {
            float4 a = *reinterpret_cast<const float4*>(kr + 4 * j);
            kf[4*j+0] = a.x; kf[4*j+1] = a.y; kf[4*j+2] = a.z; kf[4*j+3] = a.w;
            float4 b = *reinterpret_cast<const float4*>(vr + 4 * j);
            vf[4*j+0] = b.x; vf[4*j+1] = b.y; vf[4*j+2] = b.z; vf[4*j+3] = b.w;
        }
        float bp0 = 0.f, bp1 = 0.f, bp2 = 0.f, bp3 = 0.f;
#pragma unroll
        for (int j = 0; j < 4; ++j) {
            bp0 = fmaf(qfB[4*j+0], kf[4*j+0], bp0);
            bp1 = fmaf(qfB[4*j+1], kf[4*j+1], bp1);
            bp2 = fmaf(qfB[4*j+2], kf[4*j+2], bp2);
            bp3 = fmaf(qfB[4*j+3], kf[4*j+3], bp3);
        }
        float pb = (bp0 + bp1) + (bp2 + bp3);
        float pa = 0.f;
        if (DOA) {
            float ap0 = 0.f, ap1 = 0.f, ap2 = 0.f, ap3 = 0.f;
#pragma unroll
            for (int j = 0; j < 4; ++j) {
                ap0 = fmaf(qfA[4*j+0], kf[4*j+0], ap0);
                ap1 = fmaf(qfA[4*j+1], kf[4*j+1], ap1);
                ap2 = fmaf(qfA[4*j+2], kf[4*j+2], ap2);
                ap3 = fmaf(qfA[4*j+3], kf[4*j+3], ap3);
            }
            pa = (ap0 + ap1) + (ap2 + ap3);
        }
        pb += __shfl_xor(pb, 1);
        pb += __shfl_xor(pb, 2);
        if (DOA) { pa += __shfl_xor(pa, 1); pa += __shfl_xor(pa, 2); }

        float wB = pb * pb * etB;
        if (MODE == 3) wB = (sl <= row) ? wB : 0.f;
        denB += wB;
#pragma unroll
        for (int j = 0; j < 16; ++j) accB[j] = fmaf(wB, vf[j], accB[j]);
        if (DOA) {
            float wA = pa * pa * etA;
            if (MODE == 1) wA = (sl <= row) ? wA : 0.f;
            denA += wA;
#pragma unroll
            for (int j = 0; j < 16; ++j) accA[j] = fmaf(wA, vf[j], accA[j]);
        }
    }
}

__global__ __launch_bounds__(256)
void retention_fwd_fb(const float* __restrict__ q, const float* __restrict__ k,
                      const float* __restrict__ v, const float* __restrict__ gc,
                      float* __restrict__ out) {
    const int pair  = blockIdx.x;
    const int h     = blockIdx.y;
    const int A     = pair;
    const int Btile = NT - 1 - pair;

    const int tid = threadIdx.x;
    const int row = tid >> 2;
    const int c   = tid & 3;
    const int tA  = A * QTILE + row;
    const int tB  = Btile * QTILE + row;

    __shared__ float kt[STILE][D_DIM];
    __shared__ float vt[STILE][D_DIM];

    const float* gch = gc + (size_t)h * T_DIM;
    const float gctA = gch[tA];
    const float gctB = gch[tB];

    float qfA[16], qfB[16];
    {
        const float* qra = q + ((size_t)tA * H_DIM + h) * D_DIM + c * 16;
        const float* qrb = q + ((size_t)tB * H_DIM + h) * D_DIM + c * 16;
#pragma unroll
        for (int j = 0; j < 4; ++j) {
            float4 fa = *reinterpret_cast<const float4*>(qra + 4 * j);
            qfA[4*j+0] = fa.x; qfA[4*j+1] = fa.y; qfA[4*j+2] = fa.z; qfA[4*j+3] = fa.w;
            float4 fb = *reinterpret_cast<const float4*>(qrb + 4 * j);
            qfB[4*j+0] = fb.x; qfB[4*j+1] = fb.y; qfB[4*j+2] = fb.z; qfB[4*j+3] = fb.w;
        }
    }
    float accA[16], accB[16];
#pragma unroll
    for (int j = 0; j < 16; ++j) { accA[j] = 0.f; accB[j] = 0.f; }
    float denA = 0.f, denB = 0.f;

    for (int st = 0; st <= Btile; ++st) {
        const int s0 = st * STILE;
        __syncthreads();
        const float gb = gch[s0];
        for (int i = tid; i < STILE * 16; i += 256) {
            const int srow = i >> 4;
            const int ccol = (i & 15) * 4;
            const float se = __expf((gb - gch[s0 + srow]) * 0.5f);
            const size_t gidx = ((size_t)(s0 + srow) * H_DIM + h) * D_DIM + ccol;
            float4 kf4 = *reinterpret_cast<const float4*>(k + gidx);
            kf4.x *= se; kf4.y *= se; kf4.z *= se; kf4.w *= se;
            *reinterpret_cast<float4*>(&kt[srow][ccol]) = kf4;
            *reinterpret_cast<float4*>(&vt[srow][ccol]) =
                *reinterpret_cast<const float4*>(v + gidx);
        }
        __syncthreads();
        const float etA = __expf(gctA - gb) * (SCALE_F * SCALE_F);
        const float etB = __expf(gctB - gb) * (SCALE_F * SCALE_F);
        if (st < A)
            tile_inner_fb<0>(kt, vt, row, c, qfA, qfB, etA, etB, accA, accB, denA, denB);
        else if (st == A)
            tile_inner_fb<1>(kt, vt, row, c, qfA, qfB, etA, etB, accA, accB, denA, denB);
        else if (st < Btile)
            tile_inner_fb<2>(kt, vt, row, c, qfA, qfB, etA, etB, accA, accB, denA, denB);
        else
            tile_inner_fb<3>(kt, vt, row, c, qfA, qfB, etA, etB, accA, accB, denA, denB);
    }
    {
        const float invA = 1.f / fmaxf(denA, 1.0f);
        const float invB = 1.f / fmaxf(denB, 1.0f);
        float* oa = out + ((size_t)tA * H_DIM + h) * D_DIM + c * 16;
        float* ob = out + ((size_t)tB * H_DIM + h) * D_DIM + c * 16;
#pragma unroll
        for (int j = 0; j < 4; ++j) {
            float4 fa, fb;
            fa.x = accA[4*j+0] * invA; fa.y = accA[4*j+1] * invA;
            fa.z = accA[4*j+2] * invA; fa.w = accA[4*j+3] * invA;
            *reinterpret_cast<float4*>(oa + 4 * j) = fa;
            fb.x = accB[4*j+0] * invB; fb.y = accB[4*j+1] * invB;
            fb.z = accB[4*j+2] * invB; fb.w = accB[4*j+3] * invB;
            *reinterpret_cast<float4*>(ob + 4 * j) = fb;
        }
    }
}

// ---------------------------------------------------------------------------
extern "C" void kernel_launch(void* const* d_in, const int* in_sizes, int n_in,
                              void* d_out, int out_size, void* d_ws, size_t ws_size,
                              hipStream_t stream) {
    const float* q = (const float*)d_in[0];
    const float* k = (const float*)d_in[1];
    const float* v = (const float*)d_in[2];
    const float* g = (const float*)d_in[3];
    float* out = (float*)d_out;

    const size_t GC_BYTES = (size_t)H_DIM * T_DIM * sizeof(float);        // 256 KB
    const size_t BF_ELEMS = (size_t)H_DIM * T_DIM * D_DIM;                // 4.2M
    const size_t BF_BYTES = BF_ELEMS * sizeof(ushort);                    // 8.4 MB
    const size_t NEED = GC_BYTES + 3 * BF_BYTES;

    float* gc = (float*)d_ws;
    cumsum_g_kernel<<<H_DIM, 256, 0, stream>>>(g, gc);

    if (ws_size >= NEED) {
        ushort* qh = (ushort*)((char*)d_ws + GC_BYTES);
        ushort* kh = qh + BF_ELEMS;
        ushort* vT = kh + BF_ELEMS;

        prep_kernel<<<dim3(NT, H_DIM), 256, 0, stream>>>(q, k, v, gc, qh, kh, vT);
        retention_mfma_kernel<<<NPAIR * H_DIM, 256, 0, stream>>>(qh, kh, vT, out);
    } else {
        dim3 grid(NPAIR, H_DIM);
        retention_fwd_fb<<<grid, 256, 0, stream>>>(q, k, v, gc, out);
    }
}

// Round 4
// 47.881 us; speedup vs baseline: 15.6727x; 1.8140x over previous
//
#include <hip/hip_runtime.h>

// Problem constants (reference: B=1, T=2048, H=32, D=64, SCALE=1/64, DEG=2)
#define T_DIM 2048
#define H_DIM 32
#define D_DIM 64
#define SCALE_F 0.015625f
#define NPAIR 32            // folded pairs of 32-row q-subtiles (64 subtiles)
#define TILE_STRIDE 2048    // ushorts per (h, 32-row tile) frag block = 4KB

typedef unsigned short ushort;
typedef __attribute__((ext_vector_type(8))) short short8;   // 8 bf16
typedef __attribute__((ext_vector_type(16))) float f32x16;  // 32x32 MFMA acc

// ---------------------------------------------------------------------------
// Kernel 1: per-head inclusive cumsum of g over T -> gc stored [H][T]  (B=1)
// ---------------------------------------------------------------------------
__global__ __launch_bounds__(256)
void cumsum_g_kernel(const float* __restrict__ g, float* __restrict__ gc) {
    const int h = blockIdx.x;
    const int tid = threadIdx.x;
    const int PER = T_DIM / 256;        // 8

    __shared__ float sums[256];

    float loc[8];
    float run = 0.f;
    const int t0 = tid * PER;
    for (int i = 0; i < PER; ++i) {
        run += g[(size_t)(t0 + i) * H_DIM + h];
        loc[i] = run;
    }
    sums[tid] = run;
    __syncthreads();

    for (int off = 1; off < 256; off <<= 1) {
        float vv = (tid >= off) ? sums[tid - off] : 0.f;
        __syncthreads();
        sums[tid] += vv;
        __syncthreads();
    }
    float excl = (tid == 0) ? 0.f : sums[tid - 1];

    for (int i = 0; i < PER; ++i)
        gc[(size_t)h * T_DIM + t0 + i] = excl + loc[i];
}

// ---------------------------------------------------------------------------
__device__ __forceinline__ ushort f2bf(float x) {
    unsigned u = __float_as_uint(x);
    unsigned r = (u + 0x7fffu + ((u >> 16) & 1u)) >> 16;
    return (ushort)r;
}

// ---------------------------------------------------------------------------
// Prep: write frag-major bf16 buffers so ALL main-loop frag loads coalesce.
//   qfrag/kfrag: [h][t32][ks(4)][hi(2)][l31(32)][8]  content q̂/k̂[32*t32+l31][16ks+8hi+j]
//   vfrag:       [h][s32][dblk(2)][kh2(2)][hi(2)][l31(32)][8]
//                 content v̂[32*s32+16kh2+8hi+j][32dblk+l31]
// q̂ = q*SCALE*exp(gc/2), k̂ = k*exp(-gc/2), v̂ = bf16(v).
// Block = (64-row chunk tt, head h), 256 threads.
// ---------------------------------------------------------------------------
__global__ __launch_bounds__(256)
void prep_kernel(const float* __restrict__ q, const float* __restrict__ k,
                 const float* __restrict__ v, const float* __restrict__ gc,
                 ushort* __restrict__ qfrag, ushort* __restrict__ kfrag,
                 ushort* __restrict__ vfrag) {
    __shared__ ushort qt_l[64 * 64];   // swizzled [row][slot] 16B chunks
    __shared__ ushort kt_l[64 * 64];

    const int tt  = blockIdx.x;        // 64-row chunk
    const int h   = blockIdx.y;
    const int tid = threadIdx.x;

    // ---- stage q̂,k̂ rows into swizzled LDS (coalesced f32 reads) ----
    {
        const int r    = tid >> 2;          // 0..63
        const int dseg = (tid & 3) * 16;    // 16 floats
        const int t    = tt * 64 + r;
        const float gct = gc[(size_t)h * T_DIM + t];
        const float eq = SCALE_F * __expf(0.5f * gct);
        const float ek = __expf(-0.5f * gct);
        const float* qp = q + ((size_t)t * H_DIM + h) * 64 + dseg;
        const float* kp = k + ((size_t)t * H_DIM + h) * 64 + dseg;
        union { ushort u[16]; uint4 uu[2]; } oq, ok;
#pragma unroll
        for (int i = 0; i < 16; ++i) {
            oq.u[i] = f2bf(qp[i] * eq);
            ok.u[i] = f2bf(kp[i] * ek);
        }
        const int c0 = (tid & 3) * 2;       // 16B chunk index base
#pragma unroll
        for (int cc = 0; cc < 2; ++cc) {
            const int slot = (c0 + cc) ^ (r & 7);
            *reinterpret_cast<uint4*>(&qt_l[r * 64 + slot * 8]) = oq.uu[cc];
            *reinterpret_cast<uint4*>(&kt_l[r * 64 + slot * 8]) = ok.uu[cc];
        }
    }
    __syncthreads();

    // ---- q/k frag writes: 512 16B-chunks each, coalesced stores ----
#pragma unroll
    for (int n = 0; n < 2; ++n) {
        const int ch   = tid + 256 * n;     // 0..511
        const int l31  = ch & 31;
        const int hi   = (ch >> 5) & 1;
        const int ks   = (ch >> 6) & 3;
        const int t32r = ch >> 8;           // 0/1
        const int row  = t32r * 32 + l31;
        const int slot = (2 * ks + hi) ^ (row & 7);
        uint4 qq = *reinterpret_cast<const uint4*>(&qt_l[row * 64 + slot * 8]);
        uint4 kk = *reinterpret_cast<const uint4*>(&kt_l[row * 64 + slot * 8]);
        const size_t base = ((size_t)h * 64 + tt * 2 + t32r) * TILE_STRIDE
                          + (size_t)(((ks * 2 + hi) * 32) + l31) * 8;
        *reinterpret_cast<uint4*>(qfrag + base) = qq;
        *reinterpret_cast<uint4*>(kfrag + base) = kk;
    }

    // ---- v frags: direct global gather (all loads/stores coalesced) ----
#pragma unroll
    for (int n = 0; n < 2; ++n) {
        const int c9   = (tid >> 5) + 8 * n;  // 0..15
        const int l31  = tid & 31;
        const int hi   = c9 & 1;
        const int kh2  = (c9 >> 1) & 1;
        const int dblk = (c9 >> 2) & 1;
        const int s32r = c9 >> 3;
        const int tb = tt * 64 + s32r * 32 + kh2 * 16 + hi * 8;
        union { ushort u[8]; uint4 uu; } ov;
#pragma unroll
        for (int j = 0; j < 8; ++j)
            ov.u[j] = f2bf(v[((size_t)(tb + j) * H_DIM + h) * 64 + dblk * 32 + l31]);
        const size_t base = ((size_t)h * 64 + tt * 2 + s32r) * TILE_STRIDE
                          + (size_t)((((dblk * 2 + kh2) * 2 + hi) * 32) + l31) * 8;
        *reinterpret_cast<uint4*>(vfrag + base) = ov.uu;
    }
}

// ---------------------------------------------------------------------------
// Main kernel helpers
// ---------------------------------------------------------------------------
__device__ __forceinline__ short8 ld8(const ushort* p) {
    return *reinterpret_cast<const short8*>(p);
}

__device__ __forceinline__ unsigned cvt_pk_bf16(float lo, float hi) {
    unsigned r;
    asm("v_cvt_pk_bf16_f32 %0, %1, %2" : "=v"(r) : "v"(lo), "v"(hi));
    return r;
}

// One 32-s step: S^T = K̂·Q̂^T (4 MFMA), square+mask, pack via cvt_pk+permlane,
// PV (4 MFMA). All frag loads are single coalesced dwordx4.
template<bool DIAG>
__device__ __forceinline__ void step32(
    const ushort* __restrict__ kb, const ushort* __restrict__ vb,
    int lofs, int hi, int l31,
    const short8 (&qr)[4], f32x16& o0, f32x16& o1, float& den)
{
    const short8 vf00 = ld8(vb + lofs);           // dblk0 kh2=0
    const short8 vf10 = ld8(vb + 512 + lofs);     // dblk0 kh2=1
    const short8 vf01 = ld8(vb + 1024 + lofs);    // dblk1 kh2=0
    const short8 vf11 = ld8(vb + 1536 + lofs);    // dblk1 kh2=1
    const short8 kf0 = ld8(kb + lofs);
    const short8 kf1 = ld8(kb + 512 + lofs);
    const short8 kf2 = ld8(kb + 1024 + lofs);
    const short8 kf3 = ld8(kb + 1536 + lofs);

    f32x16 c;
#pragma unroll
    for (int i = 0; i < 16; ++i) c[i] = 0.f;
    c = __builtin_amdgcn_mfma_f32_32x32x16_bf16(kf0, qr[0], c, 0, 0, 0);
    c = __builtin_amdgcn_mfma_f32_32x32x16_bf16(kf1, qr[1], c, 0, 0, 0);
    c = __builtin_amdgcn_mfma_f32_32x32x16_bf16(kf2, qr[2], c, 0, 0, 0);
    c = __builtin_amdgcn_mfma_f32_32x32x16_bf16(kf3, qr[3], c, 0, 0, 0);

    float w[16];
#pragma unroll
    for (int r = 0; r < 16; ++r) {
        float x = c[r];
        float ww = x * x;
        if (DIAG) {
            const int s_local = (r & 3) + 8 * (r >> 2) + 4 * hi;
            ww = (s_local <= l31) ? ww : 0.f;
        }
        w[r] = ww;
        den += ww;
    }

#pragma unroll
    for (int kh2 = 0; kh2 < 2; ++kh2) {
        const int b = 8 * kh2;
        unsigned p0 = cvt_pk_bf16(w[b + 0], w[b + 1]);
        unsigned p1 = cvt_pk_bf16(w[b + 2], w[b + 3]);
        unsigned p2 = cvt_pk_bf16(w[b + 4], w[b + 5]);
        unsigned p3 = cvt_pk_bf16(w[b + 6], w[b + 7]);
        asm("v_permlane32_swap_b32 %0, %1" : "+v"(p0), "+v"(p2));
        asm("v_permlane32_swap_b32 %0, %1" : "+v"(p1), "+v"(p3));
        union { unsigned u[4]; short8 s; } af;
        af.u[0] = p0; af.u[1] = p1; af.u[2] = p2; af.u[3] = p3;
        if (kh2 == 0) {
            o0 = __builtin_amdgcn_mfma_f32_32x32x16_bf16(af.s, vf00, o0, 0, 0, 0);
            o1 = __builtin_amdgcn_mfma_f32_32x32x16_bf16(af.s, vf01, o1, 0, 0, 0);
        } else {
            o0 = __builtin_amdgcn_mfma_f32_32x32x16_bf16(af.s, vf10, o0, 0, 0, 0);
            o1 = __builtin_amdgcn_mfma_f32_32x32x16_bf16(af.s, vf11, o1, 0, 0, 0);
        }
    }
}

// Process one 32-row q-subtile oo. 4 waves split-K over s-steps (st ≡ w mod 4),
// then LDS-reduce partials. Wave w finalizes output rows 8w..8w+7.
__device__ __forceinline__ void process_subtile(
    int oo, int h, int w, int hi, int l31, int lofs,
    const ushort* __restrict__ qfrag, const ushort* __restrict__ kfrag,
    const ushort* __restrict__ vfrag, float* __restrict__ out,
    float* lds_o, float* lds_den)
{
    short8 qr[4];
    const ushort* qb = qfrag + ((size_t)h * 64 + oo) * TILE_STRIDE;
#pragma unroll
    for (int ks = 0; ks < 4; ++ks) qr[ks] = ld8(qb + ks * 512 + lofs);

    f32x16 o0, o1;
#pragma unroll
    for (int i = 0; i < 16; ++i) { o0[i] = 0.f; o1[i] = 0.f; }
    float den = 0.f;

    const ushort* kh_b = kfrag + (size_t)h * 64 * TILE_STRIDE;
    const ushort* vh_b = vfrag + (size_t)h * 64 * TILE_STRIDE;

    for (int st = w; st < oo; st += 4)
        step32<false>(kh_b + (size_t)st * TILE_STRIDE, vh_b + (size_t)st * TILE_STRIDE,
                      lofs, hi, l31, qr, o0, o1, den);
    if ((oo & 3) == w)   // this wave owns the diagonal step
        step32<true>(kh_b + (size_t)oo * TILE_STRIDE, vh_b + (size_t)oo * TILE_STRIDE,
                     lofs, hi, l31, qr, o0, o1, den);

    den += __shfl_xor(den, 32);

    __syncthreads();
#pragma unroll
    for (int r = 0; r < 16; ++r) {
        const int row = (r & 3) + 8 * (r >> 2) + 4 * hi;
        lds_o[((w * 2 + 0) * 32 + row) * 32 + l31] = o0[r];
        lds_o[((w * 2 + 1) * 32 + row) * 32 + l31] = o1[r];
    }
    if (hi == 0) lds_den[w * 32 + l31] = den;
    __syncthreads();

    const float dtot = lds_den[l31] + lds_den[32 + l31] +
                       lds_den[64 + l31] + lds_den[96 + l31];
    const int t0 = oo * 32;
#pragma unroll
    for (int qq = 0; qq < 4; ++qq) {
        const int row = qq + 8 * w + 4 * hi;
        float s0 = 0.f, s1 = 0.f;
#pragma unroll
        for (int ww = 0; ww < 4; ++ww) {
            s0 += lds_o[((ww * 2 + 0) * 32 + row) * 32 + l31];
            s1 += lds_o[((ww * 2 + 1) * 32 + row) * 32 + l31];
        }
        const float dt = __shfl(dtot, row);
        const float inv = 1.f / fmaxf(dt, 1.f);
        float* op = out + ((size_t)(t0 + row) * H_DIM + h) * 64;
        op[l31]      = s0 * inv;
        op[32 + l31] = s1 * inv;
    }
}

// ---------------------------------------------------------------------------
// Kernel 3: grid 1024 = 32 pairs x 32 heads, 4 waves, all frag loads coalesced.
// Pair p handles subtiles (63-p) then (p): uniform 65 s-steps per block.
// ---------------------------------------------------------------------------
__global__ __launch_bounds__(256, 4)
void retention_mfma_kernel(const ushort* __restrict__ qfrag,
                           const ushort* __restrict__ kfrag,
                           const ushort* __restrict__ vfrag,
                           float* __restrict__ out) {
    __shared__ float lds_o[4 * 2 * 32 * 32];   // 32 KB partials
    __shared__ float lds_den[4 * 32];

    const int bid = blockIdx.x;
    const int p   = bid >> 5;          // pair 0..31
    const int h   = bid & 31;          // head fastest -> 4 heads per XCD
    const int lane = threadIdx.x & 63;
    const int w    = threadIdx.x >> 6; // wave 0..3 (split-K role)
    const int hi   = lane >> 5;
    const int l31  = lane & 31;
    const int lofs = hi * 256 + l31 * 8;

    process_subtile(63 - p, h, w, hi, l31, lofs, qfrag, kfrag, vfrag, out, lds_o, lds_den);
    process_subtile(p,      h, w, hi, l31, lofs, qfrag, kfrag, vfrag, out, lds_o, lds_den);
}

// ---------------------------------------------------------------------------
extern "C" void kernel_launch(void* const* d_in, const int* in_sizes, int n_in,
                              void* d_out, int out_size, void* d_ws, size_t ws_size,
                              hipStream_t stream) {
    const float* q = (const float*)d_in[0];
    const float* k = (const float*)d_in[1];
    const float* v = (const float*)d_in[2];
    const float* g = (const float*)d_in[3];
    float* out = (float*)d_out;

    const size_t GC_BYTES = (size_t)H_DIM * T_DIM * sizeof(float);   // 256 KB
    const size_t BF_ELEMS = (size_t)H_DIM * T_DIM * D_DIM;           // 4.2M ushorts

    float* gc = (float*)d_ws;
    ushort* qfrag = (ushort*)((char*)d_ws + GC_BYTES);
    ushort* kfrag = qfrag + BF_ELEMS;
    ushort* vfrag = kfrag + BF_ELEMS;

    cumsum_g_kernel<<<H_DIM, 256, 0, stream>>>(g, gc);
    prep_kernel<<<dim3(T_DIM / 64, H_DIM), 256, 0, stream>>>(q, k, v, gc,
                                                             qfrag, kfrag, vfrag);
    retention_mfma_kernel<<<NPAIR * H_DIM, 256, 0, stream>>>(qfrag, kfrag, vfrag, out);
}

// Round 5
// 45.469 us; speedup vs baseline: 16.5042x; 1.0531x over previous
//
#include <hip/hip_runtime.h>

// Problem constants (reference: B=1, T=2048, H=32, D=64, SCALE=1/64, DEG=2)
#define T_DIM 2048
#define H_DIM 32
#define D_DIM 64
#define SCALE_F 0.015625f
#define TILE_STRIDE 2048    // ushorts per (h, 32-row frag tile) = 4KB

typedef unsigned short ushort;
typedef __attribute__((ext_vector_type(8))) short short8;   // 8 bf16
typedef __attribute__((ext_vector_type(16))) float f32x16;  // 32x32 MFMA acc

// ---------------------------------------------------------------------------
// Kernel 1: per-head inclusive cumsum of g over T -> gc stored [H][T]  (B=1)
// ---------------------------------------------------------------------------
__global__ __launch_bounds__(256)
void cumsum_g_kernel(const float* __restrict__ g, float* __restrict__ gc) {
    const int h = blockIdx.x;
    const int tid = threadIdx.x;
    const int PER = T_DIM / 256;        // 8

    __shared__ float sums[256];

    float loc[8];
    float run = 0.f;
    const int t0 = tid * PER;
    for (int i = 0; i < PER; ++i) {
        run += g[(size_t)(t0 + i) * H_DIM + h];
        loc[i] = run;
    }
    sums[tid] = run;
    __syncthreads();

    for (int off = 1; off < 256; off <<= 1) {
        float vv = (tid >= off) ? sums[tid - off] : 0.f;
        __syncthreads();
        sums[tid] += vv;
        __syncthreads();
    }
    float excl = (tid == 0) ? 0.f : sums[tid - 1];

    for (int i = 0; i < PER; ++i)
        gc[(size_t)h * T_DIM + t0 + i] = excl + loc[i];
}

// ---------------------------------------------------------------------------
__device__ __forceinline__ ushort f2bf(float x) {
    unsigned u = __float_as_uint(x);
    unsigned r = (u + 0x7fffu + ((u >> 16) & 1u)) >> 16;
    return (ushort)r;
}

// ---------------------------------------------------------------------------
// Prep: frag-major bf16 buffers so ALL main-loop frag loads coalesce.
//   qfrag/kfrag: [h][t32][ks(4)][hi(2)][l31(32)][8]  content q̂/k̂[32*t32+l31][16ks+8hi+j]
//   vfrag:       [h][s32][dblk(2)][kh2(2)][hi(2)][l31(32)][8]
//                 content v̂[32*s32+16kh2+8hi+j][32dblk+l31]
// q̂ = q*SCALE*exp(gc/2), k̂ = k*exp(-gc/2), v̂ = bf16(v).
// Grid (H, T/64) so bid%8 == h%8 — frags produced on consumer's XCD L2.
// ---------------------------------------------------------------------------
__global__ __launch_bounds__(256)
void prep_kernel(const float* __restrict__ q, const float* __restrict__ k,
                 const float* __restrict__ v, const float* __restrict__ gc,
                 ushort* __restrict__ qfrag, ushort* __restrict__ kfrag,
                 ushort* __restrict__ vfrag) {
    __shared__ ushort qt_l[64 * 64];   // swizzled [row][slot] 16B chunks
    __shared__ ushort kt_l[64 * 64];

    const int h   = blockIdx.x;
    const int tt  = blockIdx.y;        // 64-row chunk
    const int tid = threadIdx.x;

    // ---- stage q̂,k̂ rows into swizzled LDS (coalesced f32 reads) ----
    {
        const int r    = tid >> 2;          // 0..63
        const int dseg = (tid & 3) * 16;    // 16 floats
        const int t    = tt * 64 + r;
        const float gct = gc[(size_t)h * T_DIM + t];
        const float eq = SCALE_F * __expf(0.5f * gct);
        const float ek = __expf(-0.5f * gct);
        const float* qp = q + ((size_t)t * H_DIM + h) * 64 + dseg;
        const float* kp = k + ((size_t)t * H_DIM + h) * 64 + dseg;
        union { ushort u[16]; uint4 uu[2]; } oq, ok;
#pragma unroll
        for (int i = 0; i < 16; ++i) {
            oq.u[i] = f2bf(qp[i] * eq);
            ok.u[i] = f2bf(kp[i] * ek);
        }
        const int c0 = (tid & 3) * 2;       // 16B chunk index base
#pragma unroll
        for (int cc = 0; cc < 2; ++cc) {
            const int slot = (c0 + cc) ^ (r & 7);
            *reinterpret_cast<uint4*>(&qt_l[r * 64 + slot * 8]) = oq.uu[cc];
            *reinterpret_cast<uint4*>(&kt_l[r * 64 + slot * 8]) = ok.uu[cc];
        }
    }
    __syncthreads();

    // ---- q/k frag writes: 512 16B-chunks each, coalesced stores ----
#pragma unroll
    for (int n = 0; n < 2; ++n) {
        const int ch   = tid + 256 * n;     // 0..511
        const int l31  = ch & 31;
        const int hi   = (ch >> 5) & 1;
        const int ks   = (ch >> 6) & 3;
        const int t32r = ch >> 8;           // 0/1
        const int row  = t32r * 32 + l31;
        const int slot = (2 * ks + hi) ^ (row & 7);
        uint4 qq = *reinterpret_cast<const uint4*>(&qt_l[row * 64 + slot * 8]);
        uint4 kk = *reinterpret_cast<const uint4*>(&kt_l[row * 64 + slot * 8]);
        const size_t base = ((size_t)h * 64 + tt * 2 + t32r) * TILE_STRIDE
                          + (size_t)(((ks * 2 + hi) * 32) + l31) * 8;
        *reinterpret_cast<uint4*>(qfrag + base) = qq;
        *reinterpret_cast<uint4*>(kfrag + base) = kk;
    }

    // ---- v frags: direct global gather (all loads/stores coalesced) ----
#pragma unroll
    for (int n = 0; n < 2; ++n) {
        const int c9   = (tid >> 5) + 8 * n;  // 0..15
        const int l31  = tid & 31;
        const int hi   = c9 & 1;
        const int kh2  = (c9 >> 1) & 1;
        const int dblk = (c9 >> 2) & 1;
        const int s32r = c9 >> 3;
        const int tb = tt * 64 + s32r * 32 + kh2 * 16 + hi * 8;
        union { ushort u[8]; uint4 uu; } ov;
#pragma unroll
        for (int j = 0; j < 8; ++j)
            ov.u[j] = f2bf(v[((size_t)(tb + j) * H_DIM + h) * 64 + dblk * 32 + l31]);
        const size_t base = ((size_t)h * 64 + tt * 2 + s32r) * TILE_STRIDE
                          + (size_t)((((dblk * 2 + kh2) * 2 + hi) * 32) + l31) * 8;
        *reinterpret_cast<uint4*>(vfrag + base) = ov.uu;
    }
}

// ---------------------------------------------------------------------------
// Main kernel helpers
// ---------------------------------------------------------------------------
__device__ __forceinline__ short8 ld8(const ushort* p) {
    return *reinterpret_cast<const short8*>(p);
}

__device__ __forceinline__ unsigned cvt_pk_bf16(float lo, float hi) {
    unsigned r;
    asm("v_cvt_pk_bf16_f32 %0, %1, %2" : "=v"(r) : "v"(lo), "v"(hi));
    return r;
}

// Pack 8 f32 W-values (one kh2 half of a 32x32 quadrant, C-layout) into the
// PV A-operand fragment via cvt_pk + permlane32_swap. (Verified R3/R4.)
__device__ __forceinline__ short8 pack_w(const float* w8) {
    unsigned p0 = cvt_pk_bf16(w8[0], w8[1]);
    unsigned p1 = cvt_pk_bf16(w8[2], w8[3]);
    unsigned p2 = cvt_pk_bf16(w8[4], w8[5]);
    unsigned p3 = cvt_pk_bf16(w8[6], w8[7]);
    asm("v_permlane32_swap_b32 %0, %1" : "+v"(p0), "+v"(p2));
    asm("v_permlane32_swap_b32 %0, %1" : "+v"(p1), "+v"(p3));
    union { unsigned u[4]; short8 s; } af;
    af.u[0] = p0; af.u[1] = p1; af.u[2] = p2; af.u[3] = p3;
    return af.s;
}

// One 32-s step against a 64-col q-tile (two 32-col halves L/H).
// 8 KB loaded -> 16 MFMA (64 FLOP/B).
// MODE 0: both halves full | 1: L diag, H full | 2: L skip, H diag.
template<int MODE>
__device__ __forceinline__ void step64(
    const ushort* __restrict__ kb, const ushort* __restrict__ vb,
    int lofs, int hi, int l31,
    const short8 (&qrL)[4], const short8 (&qrH)[4],
    f32x16& o00, f32x16& o01, f32x16& o10, f32x16& o11,
    float& denL, float& denH)
{
    const short8 vf00 = ld8(vb + lofs);           // dblk0 kh2=0
    const short8 vf10 = ld8(vb + 512 + lofs);     // dblk0 kh2=1
    const short8 vf01 = ld8(vb + 1024 + lofs);    // dblk1 kh2=0
    const short8 vf11 = ld8(vb + 1536 + lofs);    // dblk1 kh2=1
    const short8 kf0 = ld8(kb + lofs);
    const short8 kf1 = ld8(kb + 512 + lofs);
    const short8 kf2 = ld8(kb + 1024 + lofs);
    const short8 kf3 = ld8(kb + 1536 + lofs);

    f32x16 cH;
#pragma unroll
    for (int i = 0; i < 16; ++i) cH[i] = 0.f;
    f32x16 cL = cH;

    if (MODE <= 1) {
        cL = __builtin_amdgcn_mfma_f32_32x32x16_bf16(kf0, qrL[0], cL, 0, 0, 0);
        cH = __builtin_amdgcn_mfma_f32_32x32x16_bf16(kf0, qrH[0], cH, 0, 0, 0);
        cL = __builtin_amdgcn_mfma_f32_32x32x16_bf16(kf1, qrL[1], cL, 0, 0, 0);
        cH = __builtin_amdgcn_mfma_f32_32x32x16_bf16(kf1, qrH[1], cH, 0, 0, 0);
        cL = __builtin_amdgcn_mfma_f32_32x32x16_bf16(kf2, qrL[2], cL, 0, 0, 0);
        cH = __builtin_amdgcn_mfma_f32_32x32x16_bf16(kf2, qrH[2], cH, 0, 0, 0);
        cL = __builtin_amdgcn_mfma_f32_32x32x16_bf16(kf3, qrL[3], cL, 0, 0, 0);
        cH = __builtin_amdgcn_mfma_f32_32x32x16_bf16(kf3, qrH[3], cH, 0, 0, 0);
    } else {
        cH = __builtin_amdgcn_mfma_f32_32x32x16_bf16(kf0, qrH[0], cH, 0, 0, 0);
        cH = __builtin_amdgcn_mfma_f32_32x32x16_bf16(kf1, qrH[1], cH, 0, 0, 0);
        cH = __builtin_amdgcn_mfma_f32_32x32x16_bf16(kf2, qrH[2], cH, 0, 0, 0);
        cH = __builtin_amdgcn_mfma_f32_32x32x16_bf16(kf3, qrH[3], cH, 0, 0, 0);
    }

    float wL[16], wH[16];
#pragma unroll
    for (int r = 0; r < 16; ++r) {
        const int s_local = (r & 3) + 8 * (r >> 2) + 4 * hi;
        float xh = cH[r];
        float wwh = xh * xh;
        if (MODE == 2) wwh = (s_local <= l31) ? wwh : 0.f;
        wH[r] = wwh;
        denH += wwh;
        if (MODE <= 1) {
            float xl = cL[r];
            float wwl = xl * xl;
            if (MODE == 1) wwl = (s_local <= l31) ? wwl : 0.f;
            wL[r] = wwl;
            denL += wwl;
        }
    }

    if (MODE <= 1) {
        const short8 a0 = pack_w(&wL[0]);
        o00 = __builtin_amdgcn_mfma_f32_32x32x16_bf16(a0, vf00, o00, 0, 0, 0);
        o01 = __builtin_amdgcn_mfma_f32_32x32x16_bf16(a0, vf01, o01, 0, 0, 0);
        const short8 a1 = pack_w(&wL[8]);
        o00 = __builtin_amdgcn_mfma_f32_32x32x16_bf16(a1, vf10, o00, 0, 0, 0);
        o01 = __builtin_amdgcn_mfma_f32_32x32x16_bf16(a1, vf11, o01, 0, 0, 0);
    }
    {
        const short8 a0 = pack_w(&wH[0]);
        o10 = __builtin_amdgcn_mfma_f32_32x32x16_bf16(a0, vf00, o10, 0, 0, 0);
        o11 = __builtin_amdgcn_mfma_f32_32x32x16_bf16(a0, vf01, o11, 0, 0, 0);
        const short8 a1 = pack_w(&wH[8]);
        o10 = __builtin_amdgcn_mfma_f32_32x32x16_bf16(a1, vf10, o10, 0, 0, 0);
        o11 = __builtin_amdgcn_mfma_f32_32x32x16_bf16(a1, vf11, o11, 0, 0, 0);
    }
}

// Epilogue phase for one t-half: LDS-reduce 4 waves' partials + write out.
__device__ __forceinline__ void epi_phase(
    int thalf, const f32x16& od0, const f32x16& od1,
    int t0, int h, int w, int hi, int l31,
    float* __restrict__ out, float* lds_o, const float* lds_den)
{
    __syncthreads();
#pragma unroll
    for (int r = 0; r < 16; ++r) {
        const int row = (r & 3) + 8 * (r >> 2) + 4 * hi;
        lds_o[((w * 2 + 0) * 32 + row) * 32 + l31] = od0[r];
        lds_o[((w * 2 + 1) * 32 + row) * 32 + l31] = od1[r];
    }
    __syncthreads();
#pragma unroll
    for (int rr = 0; rr < 8; ++rr) {
        const int row = 8 * w + rr;
        const float s = lds_o[((0 + hi) * 32 + row) * 32 + l31]
                      + lds_o[((2 + hi) * 32 + row) * 32 + l31]
                      + lds_o[((4 + hi) * 32 + row) * 32 + l31]
                      + lds_o[((6 + hi) * 32 + row) * 32 + l31];
        const float dt = lds_den[(0 + thalf) * 32 + row]
                       + lds_den[(2 + thalf) * 32 + row]
                       + lds_den[(4 + thalf) * 32 + row]
                       + lds_den[(6 + thalf) * 32 + row];
        const float inv = 1.f / fmaxf(dt, 1.f);
        out[((size_t)(t0 + thalf * 32 + row) * H_DIM + h) * 64 + hi * 32 + l31]
            = s * inv;
    }
}

// Process one 64-row q-tile tt. 4 waves split-K over 32-row s-steps.
__device__ __forceinline__ void process_tile64(
    int tt, int h, int w, int hi, int l31, int lofs,
    const ushort* __restrict__ qfrag, const ushort* __restrict__ kfrag,
    const ushort* __restrict__ vfrag, float* __restrict__ out,
    float* lds_o, float* lds_den)
{
    short8 qrL[4], qrH[4];
    const ushort* qb = qfrag + ((size_t)h * 64 + 2 * tt) * TILE_STRIDE;
#pragma unroll
    for (int ks = 0; ks < 4; ++ks) {
        qrL[ks] = ld8(qb + ks * 512 + lofs);
        qrH[ks] = ld8(qb + TILE_STRIDE + ks * 512 + lofs);
    }

    f32x16 o00, o01, o10, o11;
#pragma unroll
    for (int i = 0; i < 16; ++i) { o00[i] = 0.f; o01[i] = 0.f; o10[i] = 0.f; o11[i] = 0.f; }
    float denL = 0.f, denH = 0.f;

    const ushort* kh_b = kfrag + (size_t)h * 64 * TILE_STRIDE;
    const ushort* vh_b = vfrag + (size_t)h * 64 * TILE_STRIDE;
    const int dlo = 2 * tt;

    for (int st = w; st < dlo; st += 4)
        step64<0>(kh_b + (size_t)st * TILE_STRIDE, vh_b + (size_t)st * TILE_STRIDE,
                  lofs, hi, l31, qrL, qrH, o00, o01, o10, o11, denL, denH);
    if ((dlo & 3) == w)
        step64<1>(kh_b + (size_t)dlo * TILE_STRIDE, vh_b + (size_t)dlo * TILE_STRIDE,
                  lofs, hi, l31, qrL, qrH, o00, o01, o10, o11, denL, denH);
    if (((dlo + 1) & 3) == w)
        step64<2>(kh_b + (size_t)(dlo + 1) * TILE_STRIDE, vh_b + (size_t)(dlo + 1) * TILE_STRIDE,
                  lofs, hi, l31, qrL, qrH, o00, o01, o10, o11, denL, denH);

    denL += __shfl_xor(denL, 32);
    denH += __shfl_xor(denH, 32);
    if (hi == 0) {
        lds_den[(w * 2 + 0) * 32 + l31] = denL;   // t-half 0, t-col l31
        lds_den[(w * 2 + 1) * 32 + l31] = denH;   // t-half 1
    }

    const int t0 = tt * 64;
    epi_phase(0, o00, o01, t0, h, w, hi, l31, out, lds_o, lds_den);
    epi_phase(1, o10, o11, t0, h, w, hi, l31, out, lds_o, lds_den);
}

// ---------------------------------------------------------------------------
// Kernel 3: grid 512 = 16 pairs x 32 heads (h = bid&31 -> all blocks of a
// head share an XCD). Block handles 64-row q-tiles (31-p) then (p): uniform
// 68 s-steps. 4 waves split-K; 16 MFMA per 8KB loaded.
// ---------------------------------------------------------------------------
__global__ __launch_bounds__(256, 2)
void retention_mfma_kernel(const ushort* __restrict__ qfrag,
                           const ushort* __restrict__ kfrag,
                           const ushort* __restrict__ vfrag,
                           float* __restrict__ out) {
    __shared__ float lds_o[4 * 2 * 32 * 32];   // 32 KB
    __shared__ float lds_den[4 * 2 * 32];      // 1 KB

    const int bid = blockIdx.x;
    const int p   = bid >> 5;          // pair 0..15
    const int h   = bid & 31;          // head fastest -> head-home XCD
    const int lane = threadIdx.x & 63;
    const int w    = threadIdx.x >> 6; // wave 0..3 (split-K role)
    const int hi   = lane >> 5;
    const int l31  = lane & 31;
    const int lofs = hi * 256 + l31 * 8;

    process_tile64(31 - p, h, w, hi, l31, lofs, qfrag, kfrag, vfrag, out, lds_o, lds_den);
    process_tile64(p,      h, w, hi, l31, lofs, qfrag, kfrag, vfrag, out, lds_o, lds_den);
}

// ---------------------------------------------------------------------------
extern "C" void kernel_launch(void* const* d_in, const int* in_sizes, int n_in,
                              void* d_out, int out_size, void* d_ws, size_t ws_size,
                              hipStream_t stream) {
    const float* q = (const float*)d_in[0];
    const float* k = (const float*)d_in[1];
    const float* v = (const float*)d_in[2];
    const float* g = (const float*)d_in[3];
    float* out = (float*)d_out;

    const size_t GC_BYTES = (size_t)H_DIM * T_DIM * sizeof(float);   // 256 KB
    const size_t BF_ELEMS = (size_t)H_DIM * T_DIM * D_DIM;           // 4.2M ushorts

    float* gc = (float*)d_ws;
    ushort* qfrag = (ushort*)((char*)d_ws + GC_BYTES);
    ushort* kfrag = qfrag + BF_ELEMS;
    ushort* vfrag = kfrag + BF_ELEMS;

    cumsum_g_kernel<<<H_DIM, 256, 0, stream>>>(g, gc);
    prep_kernel<<<dim3(H_DIM, T_DIM / 64), 256, 0, stream>>>(q, k, v, gc,
                                                             qfrag, kfrag, vfrag);
    retention_mfma_kernel<<<16 * H_DIM, 256, 0, stream>>>(qfrag, kfrag, vfrag, out);
}